// Round 6
// baseline (177.314 us; speedup 1.0000x reference)
//
#include <hip/hip_runtime.h>

#define N_NODES 32768
#define N_EDGES 65536

typedef _Float16 f16;
typedef _Float16 f16x8 __attribute__((ext_vector_type(8)));
typedef float f32x16 __attribute__((ext_vector_type(16)));
typedef unsigned int uint32;

// ---------------- ws layout ----------------
// [0, 131072)         hist    int[32768]        (memset 0 each call)
// [131072, 262144)    off     int[32768]        (written by k_scan)
// [262144, 393216)    cursor  int[32768]        (written by k_scan)
// [393216, 933888)    w2v2    f16, 66 j-rows x 8 octets x 1024 B
// [933888, 942080)    w1v2    f16, 8 octets x 1024 B
// [942080, 950272)    rootIv2 f16 (root + I), 8 octets x 1024 B
// [950272, 9338880)   msg     f16[65536 x 64]   (dst-sorted rows)
#define WS_HIST  0
#define WS_OFF   131072
#define WS_CUR   262144
#define WS_W2    393216
#define WS_W1    933888
#define WS_ROOT  942080
#define WS_MSG   950272

#define MFMA(a, b, c) __builtin_amdgcn_mfma_f32_32x32x16_f16((a), (b), (c), 0, 0, 0)

__device__ inline f16 u16_as_f16(unsigned short u) {
  union { unsigned short s; f16 h; } v; v.s = u; return v.h;
}
__device__ inline f16x8 splat8(f16 x) {
  f16x8 r;
  #pragma unroll
  for (int u = 0; u < 8; ++u) r[u] = x;
  return r;
}
__device__ inline f16x8 cvt8(float4 p0, float4 p1) {
  f16x8 a;
  a[0] = (f16)p0.x; a[1] = (f16)p0.y; a[2] = (f16)p0.z; a[3] = (f16)p0.w;
  a[4] = (f16)p1.x; a[5] = (f16)p1.y; a[6] = (f16)p1.z; a[7] = (f16)p1.w;
  return a;
}

// ============ prep: weights -> f16 fragment layouts; int degree histogram ============
// frag layout: oct = j*8 + (h>>4)*2 + ((h>>3)&1); byte = oct*1024 + col*16 + (h&7)*2
__global__ __launch_bounds__(256) void k_prep(const float* __restrict__ W1,
                                              const float* __restrict__ W2,
                                              const float* __restrict__ b2,
                                              const float* __restrict__ root,
                                              const int* __restrict__ eidx,
                                              int* __restrict__ hist,
                                              char* __restrict__ w2v2,
                                              char* __restrict__ w1v2,
                                              char* __restrict__ rootIv2) {
  int t = blockIdx.x * 256 + threadIdx.x;
  if (t < 65536) {                       // W2 rows j 0..63
    int j = t >> 10, rem = t & 1023, h = rem >> 4, c4 = rem & 15;
    float4 v = *(const float4*)(W2 + j * 4096 + h * 64 + c4 * 4);
    int oct = j * 8 + (h >> 4) * 2 + ((h >> 3) & 1);
    char* base = w2v2 + oct * 1024 + (h & 7) * 2;
    *(f16*)(base + (c4 * 4 + 0) * 16) = (f16)v.x;
    *(f16*)(base + (c4 * 4 + 1) * 16) = (f16)v.y;
    *(f16*)(base + (c4 * 4 + 2) * 16) = (f16)v.z;
    *(f16*)(base + (c4 * 4 + 3) * 16) = (f16)v.w;
  } else if (t < 66560) {                // b2 row j=64
    int u = t - 65536, h = u >> 4, c4 = u & 15;
    float4 v = *(const float4*)(b2 + h * 64 + c4 * 4);
    int oct = 512 + (h >> 4) * 2 + ((h >> 3) & 1);
    char* base = w2v2 + oct * 1024 + (h & 7) * 2;
    *(f16*)(base + (c4 * 4 + 0) * 16) = (f16)v.x;
    *(f16*)(base + (c4 * 4 + 1) * 16) = (f16)v.y;
    *(f16*)(base + (c4 * 4 + 2) * 16) = (f16)v.z;
    *(f16*)(base + (c4 * 4 + 3) * 16) = (f16)v.w;
  } else if (t < 67584) {                // zero row j=65
    int u = t - 66560, h = u >> 4, c4 = u & 15;
    int oct = 520 + (h >> 4) * 2 + ((h >> 3) & 1);
    char* base = w2v2 + oct * 1024 + (h & 7) * 2;
    #pragma unroll
    for (int q = 0; q < 4; ++q) *(f16*)(base + (c4 * 4 + q) * 16) = (f16)0.f;
  } else if (t < 68608) {                // W1
    int u = t - 67584, i = u >> 4, c4 = u & 15;
    float4 v = *(const float4*)(W1 + i * 64 + c4 * 4);
    int oct = (i >> 4) * 2 + ((i >> 3) & 1);
    char* base = w1v2 + oct * 1024 + (i & 7) * 2;
    *(f16*)(base + (c4 * 4 + 0) * 16) = (f16)v.x;
    *(f16*)(base + (c4 * 4 + 1) * 16) = (f16)v.y;
    *(f16*)(base + (c4 * 4 + 2) * 16) = (f16)v.z;
    *(f16*)(base + (c4 * 4 + 3) * 16) = (f16)v.w;
  } else if (t < 69632) {                // rootI = root + I
    int u = t - 68608, i = u >> 4, c4 = u & 15;
    float4 v = *(const float4*)(root + i * 64 + c4 * 4);
    int oct = (i >> 4) * 2 + ((i >> 3) & 1);
    char* base = rootIv2 + oct * 1024 + (i & 7) * 2;
    *(f16*)(base + (c4 * 4 + 0) * 16) = (f16)(v.x + (i == c4 * 4 + 0 ? 1.f : 0.f));
    *(f16*)(base + (c4 * 4 + 1) * 16) = (f16)(v.y + (i == c4 * 4 + 1 ? 1.f : 0.f));
    *(f16*)(base + (c4 * 4 + 2) * 16) = (f16)(v.z + (i == c4 * 4 + 2 ? 1.f : 0.f));
    *(f16*)(base + (c4 * 4 + 3) * 16) = (f16)(v.w + (i == c4 * 4 + 3 ? 1.f : 0.f));
  } else if (t < 135168) {               // int degree histogram
    int e = t - 69632;
    atomicAdd(&hist[eidx[N_EDGES + e]], 1);
  }
}

// ============ scan: exclusive prefix of hist -> off and cursor (single block) ============
__global__ __launch_bounds__(1024) void k_scan(const int* __restrict__ hist,
                                               int* __restrict__ off,
                                               int* __restrict__ cursor) {
  __shared__ int wsum[16];
  const int tid = threadIdx.x;
  const int lane = tid & 63;
  const int wv = tid >> 6;
  int v[32];
  const int base = tid * 32;
  #pragma unroll
  for (int i = 0; i < 32; ++i) v[i] = hist[base + i];
  int run = 0;
  #pragma unroll
  for (int i = 0; i < 32; ++i) { int x = v[i]; v[i] = run; run += x; }
  int inc = run;                         // inclusive wave scan of per-thread totals
  #pragma unroll
  for (int d = 1; d < 64; d <<= 1) {
    int o = __shfl_up(inc, d, 64);
    if (lane >= d) inc += o;
  }
  if (lane == 63) wsum[wv] = inc;
  __syncthreads();
  int wexcl = 0;
  for (int i = 0; i < wv; ++i) wexcl += wsum[i];
  const int texcl = wexcl + inc - run;
  #pragma unroll
  for (int i = 0; i < 32; ++i) {
    const int val = texcl + v[i];
    off[base + i] = val;
    cursor[base + i] = val;
  }
}

__device__ inline void chunk_load(f16x8 (&buf)[8], const char* p) {
  #pragma unroll
  for (int jj = 0; jj < 2; ++jj)
    #pragma unroll
    for (int kk = 0; kk < 4; ++kk)
      buf[jj * 4 + kk] = *(const f16x8*)(p + ((jj * 8 + kk * 2) << 10));
}

// ============ main: 256 blocks x 256 thr, T=4 tiles/wave; B direct from L2; pos-table scatter ============
__global__ __launch_bounds__(256, 1) void k_main(const float* __restrict__ node,
                                                 const float* __restrict__ edge,
                                                 const float* __restrict__ b1,
                                                 const int* __restrict__ eidx,
                                                 const char* __restrict__ w2v2,
                                                 const char* __restrict__ w1v2,
                                                 int* __restrict__ cursor,
                                                 f16* __restrict__ msg) {
  __shared__ char ldsH[34816];           // 256 edges x 136 B (64 j-f16 + pad)
  __shared__ int ldsPos[256];

  const int tid = threadIdx.x;
  const int lane = tid & 63;
  const int wv = tid >> 6;               // 0..3
  const int ln31 = lane & 31;
  const int half = lane >> 5;
  const int ebase = blockIdx.x * 256;

  // ---- phase 1: wave wv computes h = relu(ee@W1+b1) for tiles 2wv, 2wv+1 ----
  const char* w1p = w1v2 + half * 1024 + ln31 * 16;
  #pragma unroll
  for (int t = 0; t < 2; ++t) {
    const int tile = 2 * wv + t;
    const int e = ebase + tile * 32 + ln31;
    const float4* er = (const float4*)edge + (long)e * 16;
    f32x16 c0 = {}, c1 = {};
    #pragma unroll
    for (int kk = 0; kk < 4; ++kk) {
      f16x8 a = cvt8(er[kk * 4 + half * 2], er[kk * 4 + half * 2 + 1]);
      f16x8 bf0 = *(const f16x8*)(w1p + (kk * 2 << 10));
      f16x8 bf1 = *(const f16x8*)(w1p + (kk * 2 << 10) + 512);
      c0 = MFMA(a, bf0, c0);
      c1 = MFMA(a, bf1, c1);
    }
    const float bb0 = b1[ln31], bb1 = b1[32 + ln31];
    char* hb = ldsH + tile * 32 * 136;
    #pragma unroll
    for (int r = 0; r < 16; ++r) {
      const int m = (r & 3) + 8 * (r >> 2) + 4 * half;
      *(f16*)(hb + m * 136 + ln31 * 2)      = (f16)fmaxf(c0[r] + bb0, 0.f);
      *(f16*)(hb + m * 136 + 64 + ln31 * 2) = (f16)fmaxf(c1[r] + bb1, 0.f);
    }
  }

  const int ch = wv & 1;                 // output col half
  const int g  = wv >> 1;                // edge group: tiles 4g..4g+3

  // ---- gather x = node_emb[src] fragments, 4 tiles ----
  f16x8 xf[4][4];
  #pragma unroll
  for (int t = 0; t < 4; ++t) {
    const int e = ebase + (g * 4 + t) * 32 + ln31;
    const int s = eidx[e];
    const float4* xr = (const float4*)node + (long)s * 16;
    #pragma unroll
    for (int kk = 0; kk < 4; ++kk)
      xf[t][kk] = cvt8(xr[kk * 4 + half * 2], xr[kk * 4 + half * 2 + 1]);
  }

  // ---- prologue: bufA = chunk 0 (j 0,1) ----
  const char* wp = w2v2 + half * 1024 + ch * 512 + ln31 * 16;
  f16x8 bufA[8], bufB[8];
  chunk_load(bufA, wp);

  f32x16 acc[4] = {};
  const char* hp[4];
  #pragma unroll
  for (int t = 0; t < 4; ++t) hp[t] = ldsH + (g * 128 + t * 32 + ln31) * 136;

  __syncthreads();                       // ldsH ready

  // ---- K loop: 16 x 4 j-rows (j 0..63), reg double-buffered B ----
  for (int cp = 0; cp < 16; ++cp) {
    const char* base = wp + (cp << 15);  // j0 = 4*cp
    uint2 hv[4];
    #pragma unroll
    for (int t = 0; t < 4; ++t) hv[t] = *(const uint2*)(hp[t] + cp * 8);

    chunk_load(bufB, base + 16384);      // j 4cp+2, 4cp+3

    #pragma unroll
    for (int jj = 0; jj < 2; ++jj) {     // compute j 4cp+jj
      f16x8 sp[4];
      #pragma unroll
      for (int t = 0; t < 4; ++t)
        sp[t] = splat8(u16_as_f16((unsigned short)(hv[t].x >> (jj * 16))));
      #pragma unroll
      for (int kk = 0; kk < 4; ++kk)
        #pragma unroll
        for (int t = 0; t < 4; ++t)
          acc[t] = MFMA(xf[t][kk] * sp[t], bufA[jj * 4 + kk], acc[t]);
    }

    chunk_load(bufA, base + 32768);      // next pair (cp=15 -> j 64,65 exist)

    #pragma unroll
    for (int jj = 0; jj < 2; ++jj) {     // compute j 4cp+2+jj
      f16x8 sp[4];
      #pragma unroll
      for (int t = 0; t < 4; ++t)
        sp[t] = splat8(u16_as_f16((unsigned short)(hv[t].y >> (jj * 16))));
      #pragma unroll
      for (int kk = 0; kk < 4; ++kk)
        #pragma unroll
        for (int t = 0; t < 4; ++t)
          acc[t] = MFMA(xf[t][kk] * sp[t], bufB[jj * 4 + kk], acc[t]);
    }
  }

  // ---- epilogue: j = 64 bias row, A = x (h == 1 exactly; bufA holds j64,65) ----
  #pragma unroll
  for (int kk = 0; kk < 4; ++kk)
    #pragma unroll
    for (int t = 0; t < 4; ++t)
      acc[t] = MFMA(xf[t][kk], bufA[kk], acc[t]);

  // ---- allocate dst-sorted slots (ch0 waves), publish via LDS ----
  if (ch == 0) {
    #pragma unroll
    for (int t = 0; t < 4; ++t) {
      const int base_e = ebase + (g * 4 + t) * 32;
      #pragma unroll
      for (int r = 0; r < 16; ++r) {
        const int m = (r & 3) + 8 * (r >> 2) + 4 * half;
        if (ln31 == 0) {
          const int d = eidx[N_EDGES + base_e + m];
          ldsPos[(g * 4 + t) * 32 + m] = atomicAdd(&cursor[d], 1);
        }
      }
    }
  }
  __syncthreads();

  // ---- store msg rows (f16) at permuted positions ----
  #pragma unroll
  for (int t = 0; t < 4; ++t) {
    #pragma unroll
    for (int r = 0; r < 16; ++r) {
      const int m = (r & 3) + 8 * (r >> 2) + 4 * half;
      const int pos = ldsPos[(g * 4 + t) * 32 + m];
      msg[(long)pos * 64 + ch * 32 + ln31] = (f16)acc[t][r];
    }
  }
}

// ============ node epilogue: contiguous mean-agg + MFMA (root+I) + LayerNorm ============
__global__ __launch_bounds__(256) void k_node(const float* __restrict__ node,
                                              const f16* __restrict__ msg,
                                              const int* __restrict__ hist,
                                              const int* __restrict__ off,
                                              const char* __restrict__ rootIv2,
                                              const float* __restrict__ bias,
                                              const float* __restrict__ gamma,
                                              const float* __restrict__ beta,
                                              float* __restrict__ out) {
  const int tid = threadIdx.x;
  const int lane = tid & 63;
  const int wv = tid >> 6;
  const int ln31 = lane & 31;
  const int half = lane >> 5;
  const int nb = blockIdx.x * 128 + wv * 32;

  const char* rp = rootIv2 + half * 1024 + ln31 * 16;
  f32x16 c0 = {}, c1 = {};
  const float4* xr = (const float4*)node + (long)(nb + ln31) * 16;
  #pragma unroll
  for (int kk = 0; kk < 4; ++kk) {
    f16x8 a = cvt8(xr[kk * 4 + half * 2], xr[kk * 4 + half * 2 + 1]);
    f16x8 b0 = *(const f16x8*)(rp + (kk * 2 << 10));
    f16x8 b1f = *(const f16x8*)(rp + (kk * 2 << 10) + 512);
    c0 = MFMA(a, b0, c0);
    c1 = MFMA(a, b1f, c1);
  }
  const float bi0 = bias[ln31],  bi1 = bias[32 + ln31];
  const float g0  = gamma[ln31], g1  = gamma[32 + ln31];
  const float be0 = beta[ln31],  be1 = beta[32 + ln31];
  #pragma unroll
  for (int r = 0; r < 16; ++r) {
    const int m = (r & 3) + 8 * (r >> 2) + 4 * half;
    const int n = nb + m;
    const int cnt = hist[n];
    const int start = off[n];
    float s0 = 0.f, s1 = 0.f;
    for (int k = 0; k < cnt; ++k) {
      const f16* mr = msg + (long)(start + k) * 64;
      s0 += (float)mr[ln31];
      s1 += (float)mr[32 + ln31];
    }
    const float rd = 1.f / fmaxf((float)cnt, 1.f);
    const float pre0 = s0 * rd + c0[r] + bi0;
    const float pre1 = s1 * rd + c1[r] + bi1;
    float s = pre0 + pre1, s2 = pre0 * pre0 + pre1 * pre1;
    #pragma unroll
    for (int mk = 16; mk >= 1; mk >>= 1) {
      s  += __shfl_xor(s, mk, 64);
      s2 += __shfl_xor(s2, mk, 64);
    }
    const float mu  = s * 0.015625f;
    const float var = s2 * 0.015625f - mu * mu;
    const float inv = rsqrtf(var + 1e-5f);
    out[n * 64 + ln31]      = (pre0 - mu) * inv * g0 + be0;
    out[n * 64 + 32 + ln31] = (pre1 - mu) * inv * g1 + be1;
  }
}

extern "C" void kernel_launch(void* const* d_in, const int* in_sizes, int n_in,
                              void* d_out, int out_size, void* d_ws, size_t ws_size,
                              hipStream_t stream) {
  const float* node  = (const float*)d_in[0];
  const float* edgee = (const float*)d_in[1];
  const float* W1    = (const float*)d_in[2];
  const float* b1    = (const float*)d_in[3];
  const float* W2    = (const float*)d_in[4];
  const float* b2    = (const float*)d_in[5];
  const float* root  = (const float*)d_in[6];
  const float* bias  = (const float*)d_in[7];
  const float* gamma = (const float*)d_in[8];
  const float* beta  = (const float*)d_in[9];
  const int*   eidx  = (const int*)d_in[10];
  float* out = (float*)d_out;

  char* ws = (char*)d_ws;
  int*   hist    = (int*)(ws + WS_HIST);
  int*   off     = (int*)(ws + WS_OFF);
  int*   cursor  = (int*)(ws + WS_CUR);
  char*  w2v2    = ws + WS_W2;
  char*  w1v2    = ws + WS_W1;
  char*  rootIv2 = ws + WS_ROOT;
  f16*   msg     = (f16*)(ws + WS_MSG);

  hipMemsetAsync(hist, 0, 131072, stream);   // zero hist only

  k_prep<<<528, 256, 0, stream>>>(W1, W2, b2, root, eidx, hist, w2v2, w1v2, rootIv2);
  k_scan<<<1, 1024, 0, stream>>>(hist, off, cursor);
  k_main<<<256, 256, 0, stream>>>(node, edgee, b1, eidx, w2v2, w1v2, cursor, msg);
  k_node<<<256, 256, 0, stream>>>(node, msg, hist, off, rootIv2, bias, gamma, beta, out);
}

// Round 7
// 146.563 us; speedup vs baseline: 1.2098x; 1.2098x over previous
//
#include <hip/hip_runtime.h>

#define N_NODES 32768
#define N_EDGES 65536

typedef _Float16 f16;
typedef _Float16 f16x8 __attribute__((ext_vector_type(8)));
typedef float f32x16 __attribute__((ext_vector_type(16)));
typedef unsigned int uint32;
typedef __attribute__((address_space(3))) void lds_t;
typedef __attribute__((address_space(1))) void glb_t;

// ---------------- ws layout ----------------
// [0, 8388608)         agg     float[N*64]   (memset 0)
// [8388608, 8519680)   hist    int[32768]    (memset 0)
// [8519680, 9060352)   w2v2    f16, 66 j-rows x 8 octets x 1024 B
// [9060352, 9068544)   w1v2    f16, 8 octets x 1024 B
// [9068544, 9076736)   rootIv2 f16 (root + I), 8 octets x 1024 B
#define WS_AGG   0
#define WS_HIST  8388608
#define WS_W2    8519680
#define WS_W1    9060352
#define WS_ROOT  9068544

#define MFMA(a, b, c) __builtin_amdgcn_mfma_f32_32x32x16_f16((a), (b), (c), 0, 0, 0)

__device__ inline f16 u16_as_f16(unsigned short u) {
  union { unsigned short s; f16 h; } v; v.s = u; return v.h;
}
__device__ inline f16x8 splat8(f16 x) {
  f16x8 r;
  #pragma unroll
  for (int u = 0; u < 8; ++u) r[u] = x;
  return r;
}
__device__ inline f16x8 cvt8(float4 p0, float4 p1) {
  f16x8 a;
  a[0] = (f16)p0.x; a[1] = (f16)p0.y; a[2] = (f16)p0.z; a[3] = (f16)p0.w;
  a[4] = (f16)p1.x; a[5] = (f16)p1.y; a[6] = (f16)p1.z; a[7] = (f16)p1.w;
  return a;
}

// ============ prep: weights -> f16 fragment layouts; int degree histogram ============
// frag layout: oct = j*8 + (h>>4)*2 + ((h>>3)&1); byte = oct*1024 + col*16 + (h&7)*2
__global__ __launch_bounds__(256) void k_prep(const float* __restrict__ W1,
                                              const float* __restrict__ W2,
                                              const float* __restrict__ b2,
                                              const float* __restrict__ root,
                                              const int* __restrict__ eidx,
                                              int* __restrict__ hist,
                                              char* __restrict__ w2v2,
                                              char* __restrict__ w1v2,
                                              char* __restrict__ rootIv2) {
  int t = blockIdx.x * 256 + threadIdx.x;
  if (t < 65536) {                       // W2 rows j 0..63
    int j = t >> 10, rem = t & 1023, h = rem >> 4, c4 = rem & 15;
    float4 v = *(const float4*)(W2 + j * 4096 + h * 64 + c4 * 4);
    int oct = j * 8 + (h >> 4) * 2 + ((h >> 3) & 1);
    char* base = w2v2 + oct * 1024 + (h & 7) * 2;
    *(f16*)(base + (c4 * 4 + 0) * 16) = (f16)v.x;
    *(f16*)(base + (c4 * 4 + 1) * 16) = (f16)v.y;
    *(f16*)(base + (c4 * 4 + 2) * 16) = (f16)v.z;
    *(f16*)(base + (c4 * 4 + 3) * 16) = (f16)v.w;
  } else if (t < 66560) {                // b2 row j=64
    int u = t - 65536, h = u >> 4, c4 = u & 15;
    float4 v = *(const float4*)(b2 + h * 64 + c4 * 4);
    int oct = 512 + (h >> 4) * 2 + ((h >> 3) & 1);
    char* base = w2v2 + oct * 1024 + (h & 7) * 2;
    *(f16*)(base + (c4 * 4 + 0) * 16) = (f16)v.x;
    *(f16*)(base + (c4 * 4 + 1) * 16) = (f16)v.y;
    *(f16*)(base + (c4 * 4 + 2) * 16) = (f16)v.z;
    *(f16*)(base + (c4 * 4 + 3) * 16) = (f16)v.w;
  } else if (t < 67584) {                // zero row j=65
    int u = t - 66560, h = u >> 4, c4 = u & 15;
    int oct = 520 + (h >> 4) * 2 + ((h >> 3) & 1);
    char* base = w2v2 + oct * 1024 + (h & 7) * 2;
    #pragma unroll
    for (int q = 0; q < 4; ++q) *(f16*)(base + (c4 * 4 + q) * 16) = (f16)0.f;
  } else if (t < 68608) {                // W1
    int u = t - 67584, i = u >> 4, c4 = u & 15;
    float4 v = *(const float4*)(W1 + i * 64 + c4 * 4);
    int oct = (i >> 4) * 2 + ((i >> 3) & 1);
    char* base = w1v2 + oct * 1024 + (i & 7) * 2;
    *(f16*)(base + (c4 * 4 + 0) * 16) = (f16)v.x;
    *(f16*)(base + (c4 * 4 + 1) * 16) = (f16)v.y;
    *(f16*)(base + (c4 * 4 + 2) * 16) = (f16)v.z;
    *(f16*)(base + (c4 * 4 + 3) * 16) = (f16)v.w;
  } else if (t < 69632) {                // rootI = root + I
    int u = t - 68608, i = u >> 4, c4 = u & 15;
    float4 v = *(const float4*)(root + i * 64 + c4 * 4);
    int oct = (i >> 4) * 2 + ((i >> 3) & 1);
    char* base = rootIv2 + oct * 1024 + (i & 7) * 2;
    *(f16*)(base + (c4 * 4 + 0) * 16) = (f16)(v.x + (i == c4 * 4 + 0 ? 1.f : 0.f));
    *(f16*)(base + (c4 * 4 + 1) * 16) = (f16)(v.y + (i == c4 * 4 + 1 ? 1.f : 0.f));
    *(f16*)(base + (c4 * 4 + 2) * 16) = (f16)(v.z + (i == c4 * 4 + 2 ? 1.f : 0.f));
    *(f16*)(base + (c4 * 4 + 3) * 16) = (f16)(v.w + (i == c4 * 4 + 3 ? 1.f : 0.f));
  } else if (t < 135168) {               // int degree histogram
    int e = t - 69632;
    atomicAdd(&hist[eidx[N_EDGES + e]], 1);
  }
}

// ============ main: 512 blocks x 512 thr (2 blocks/CU, 4 waves/SIMD); W2 via global_load_lds dbuf ============
// block = 128 edges (4 tiles); wave (t = wv&3, ch = wv>>2) owns tile t, output col-half ch.
__global__ __launch_bounds__(512, 4) void k_main(const float* __restrict__ node,
                                                 const float* __restrict__ edge,
                                                 const float* __restrict__ b1,
                                                 const int* __restrict__ eidx,
                                                 const char* __restrict__ w2v2,
                                                 const char* __restrict__ w1v2,
                                                 float* __restrict__ agg) {
  __shared__ char smem[50176];           // [0,32768) W2 dbuf (2 x 16 KB); [32768,50176) ldsH 128 x 136 B

  char* ldsH = smem + 32768;
  const int tid = threadIdx.x;
  const int lane = tid & 63;
  const int wv = tid >> 6;               // 0..7
  const int ln31 = lane & 31;
  const int half = lane >> 5;
  const int t = wv & 3;                  // tile 0..3
  const int ch = wv >> 2;                // output col half
  const int ebase = blockIdx.x * 128;

  // ---- phase 1: wave (t,ch) computes h cols [32ch, 32ch+32) for tile t ----
  {
    const int e = ebase + t * 32 + ln31;
    const float4* er = (const float4*)edge + (long)e * 16;
    f32x16 c0 = {};
    #pragma unroll
    for (int kk = 0; kk < 4; ++kk) {
      f16x8 a = cvt8(er[kk * 4 + half * 2], er[kk * 4 + half * 2 + 1]);
      f16x8 bf = *(const f16x8*)(w1v2 + (kk * 2 + half) * 1024 + ch * 512 + ln31 * 16);
      c0 = MFMA(a, bf, c0);
    }
    const float bb = b1[ch * 32 + ln31];
    char* hb = ldsH + t * 32 * 136;
    #pragma unroll
    for (int r = 0; r < 16; ++r) {
      const int m = (r & 3) + 8 * (r >> 2) + 4 * half;
      *(f16*)(hb + m * 136 + (ch * 32 + ln31) * 2) = (f16)fmaxf(c0[r] + bb, 0.f);
    }
    if (ch == 1)                          // j=64 bias row -> 1.0, j=65 -> 0
      *(uint32*)(hb + ln31 * 136 + 128) = 0x00003C00u;
  }

  // ---- gather x = node_emb[src] fragments for tile t ----
  f16x8 xf[4];
  {
    const int e = ebase + t * 32 + ln31;
    const int s = eidx[e];
    const float4* xr = (const float4*)node + (long)s * 16;
    #pragma unroll
    for (int kk = 0; kk < 4; ++kk)
      xf[kk] = cvt8(xr[kk * 4 + half * 2], xr[kk * 4 + half * 2 + 1]);
  }

  // ---- stage chunk 0 ----
  {
    const char* s_ = w2v2 + tid * 16;
    char* d_ = smem + tid * 16;
    __builtin_amdgcn_global_load_lds((const glb_t*)s_, (lds_t*)d_, 16, 0, 0);
    __builtin_amdgcn_global_load_lds((const glb_t*)(s_ + 8192), (lds_t*)(d_ + 8192), 16, 0, 0);
  }

  const char* hp = ldsH + (t * 32 + ln31) * 136;
  f32x16 acc = {};

  asm volatile("s_waitcnt vmcnt(0) lgkmcnt(0)" ::: "memory");
  __builtin_amdgcn_sched_barrier(0);
  __builtin_amdgcn_s_barrier();          // chunk 0 + ldsH ready

  // ---- K loop: 33 chunks of 2 j-rows (j 0..65), LDS dbuf, one raw barrier per chunk ----
  int cur = 0;
  #pragma unroll 1
  for (int c = 0; c < 33; ++c) {
    if (c < 32) {                        // issue next-chunk loads (to the other buffer)
      const char* s_ = w2v2 + (c + 1) * 16384 + tid * 16;
      char* d_ = smem + (cur ^ 1) * 16384 + tid * 16;
      __builtin_amdgcn_global_load_lds((const glb_t*)s_, (lds_t*)d_, 16, 0, 0);
      __builtin_amdgcn_global_load_lds((const glb_t*)(s_ + 8192), (lds_t*)(d_ + 8192), 16, 0, 0);
    }
    const uint32 hv = *(const uint32*)(hp + c * 4);
    const char* bb_ = smem + cur * 16384 + half * 1024 + ch * 512 + ln31 * 16;
    __builtin_amdgcn_s_setprio(1);
    #pragma unroll
    for (int jj = 0; jj < 2; ++jj) {
      const f16x8 sp = splat8(u16_as_f16((unsigned short)(hv >> (jj * 16))));
      #pragma unroll
      for (int kk = 0; kk < 4; ++kk) {
        const f16x8 B = *(const f16x8*)(bb_ + jj * 8192 + kk * 2048);
        acc = MFMA(xf[kk] * sp, B, acc);
      }
    }
    __builtin_amdgcn_s_setprio(0);
    if (c < 32) {
      asm volatile("s_waitcnt vmcnt(0)" ::: "memory");   // next chunk landed (per-wave) ...
      __builtin_amdgcn_sched_barrier(0);
      __builtin_amdgcn_s_barrier();                      // ... and block-wide; prev buffer free
      cur ^= 1;
    }
  }

  // ---- scatter-add msg into agg[dst] ----
  {
    const int base_e = ebase + t * 32;
    #pragma unroll
    for (int r = 0; r < 16; ++r) {
      const int m = (r & 3) + 8 * (r >> 2) + 4 * half;
      const int d = eidx[N_EDGES + base_e + m];
      unsafeAtomicAdd(&agg[(long)d * 64 + ch * 32 + ln31], acc[r]);
    }
  }
}

// ============ node epilogue: MFMA (root+I) transform + mean-agg + LayerNorm ============
__global__ __launch_bounds__(256) void k_node(const float* __restrict__ node,
                                              const float* __restrict__ agg,
                                              const int* __restrict__ hist,
                                              const char* __restrict__ rootIv2,
                                              const float* __restrict__ bias,
                                              const float* __restrict__ gamma,
                                              const float* __restrict__ beta,
                                              float* __restrict__ out) {
  const int tid = threadIdx.x;
  const int lane = tid & 63;
  const int wv = tid >> 6;
  const int ln31 = lane & 31;
  const int half = lane >> 5;
  const int nb = blockIdx.x * 128 + wv * 32;

  const char* rp = rootIv2 + half * 1024 + ln31 * 16;
  f32x16 c0 = {}, c1 = {};
  const float4* xr = (const float4*)node + (long)(nb + ln31) * 16;
  #pragma unroll
  for (int kk = 0; kk < 4; ++kk) {
    f16x8 a = cvt8(xr[kk * 4 + half * 2], xr[kk * 4 + half * 2 + 1]);
    f16x8 b0 = *(const f16x8*)(rp + (kk * 2 << 10));
    f16x8 b1f = *(const f16x8*)(rp + (kk * 2 << 10) + 512);
    c0 = MFMA(a, b0, c0);
    c1 = MFMA(a, b1f, c1);
  }
  const float bi0 = bias[ln31],  bi1 = bias[32 + ln31];
  const float g0  = gamma[ln31], g1  = gamma[32 + ln31];
  const float be0 = beta[ln31],  be1 = beta[32 + ln31];
  #pragma unroll
  for (int r = 0; r < 16; ++r) {
    const int m = (r & 3) + 8 * (r >> 2) + 4 * half;
    const int n = nb + m;
    const float rd = 1.f / fmaxf((float)hist[n], 1.f);
    const float pre0 = agg[n * 64 + ln31] * rd + c0[r] + bi0;
    const float pre1 = agg[n * 64 + 32 + ln31] * rd + c1[r] + bi1;
    float s = pre0 + pre1, s2 = pre0 * pre0 + pre1 * pre1;
    #pragma unroll
    for (int mk = 16; mk >= 1; mk >>= 1) {
      s  += __shfl_xor(s, mk, 64);
      s2 += __shfl_xor(s2, mk, 64);
    }
    const float mu  = s * 0.015625f;
    const float var = s2 * 0.015625f - mu * mu;
    const float inv = rsqrtf(var + 1e-5f);
    out[n * 64 + ln31]      = (pre0 - mu) * inv * g0 + be0;
    out[n * 64 + 32 + ln31] = (pre1 - mu) * inv * g1 + be1;
  }
}

extern "C" void kernel_launch(void* const* d_in, const int* in_sizes, int n_in,
                              void* d_out, int out_size, void* d_ws, size_t ws_size,
                              hipStream_t stream) {
  const float* node  = (const float*)d_in[0];
  const float* edgee = (const float*)d_in[1];
  const float* W1    = (const float*)d_in[2];
  const float* b1    = (const float*)d_in[3];
  const float* W2    = (const float*)d_in[4];
  const float* b2    = (const float*)d_in[5];
  const float* root  = (const float*)d_in[6];
  const float* bias  = (const float*)d_in[7];
  const float* gamma = (const float*)d_in[8];
  const float* beta  = (const float*)d_in[9];
  const int*   eidx  = (const int*)d_in[10];
  float* out = (float*)d_out;

  char* ws = (char*)d_ws;
  float* agg     = (float*)(ws + WS_AGG);
  int*   hist    = (int*)(ws + WS_HIST);
  char*  w2v2    = ws + WS_W2;
  char*  w1v2    = ws + WS_W1;
  char*  rootIv2 = ws + WS_ROOT;

  hipMemsetAsync(ws, 0, 8519680, stream);   // zero agg + hist

  k_prep<<<528, 256, 0, stream>>>(W1, W2, b2, root, eidx, hist, w2v2, w1v2, rootIv2);
  k_main<<<512, 512, 0, stream>>>(node, edgee, b1, eidx, w2v2, w1v2, agg);
  k_node<<<256, 256, 0, stream>>>(node, agg, hist, rootIv2, bias, gamma, beta, out);
}